// Round 7
// baseline (381.596 us; speedup 1.0000x reference)
//
#include <hip/hip_runtime.h>
#include <hip/hip_cooperative_groups.h>
#include <hip/hip_bf16.h>
#include <math.h>

namespace cg = cooperative_groups;

// Problem constants: N=10000, E=160000, D=128, H=4, C=128, HC=512
#define D_DIM 128
#define HC_DIM 512

typedef __attribute__((ext_vector_type(8))) short bf16x8;
typedef __attribute__((ext_vector_type(4))) float f32x4;
typedef __attribute__((ext_vector_type(2))) float f32x2;

static __device__ __forceinline__ unsigned short f2bf(float f) {
  unsigned u = __float_as_uint(f);
  unsigned r = (u + 0x7fffu + ((u >> 16) & 1u)) >> 16;  // RNE
  return (unsigned short)r;
}
static __device__ __forceinline__ float bflo(unsigned u) {
  return __uint_as_float(u << 16);
}
static __device__ __forceinline__ float bfhi(unsigned u) {
  return __uint_as_float(u & 0xffff0000u);
}

// ---------------------------------------------------------------------------
// prep: cast x -> bf16; build Wt [1664][128] bf16 (coalesced source reads);
// bcat[1664]; zero counter region (cnt|cur|colsum|colsq).
// ---------------------------------------------------------------------------
__global__ void prep_kernel(const float* __restrict__ x,
                            const float* __restrict__ Wq, const float* __restrict__ Wk,
                            const float* __restrict__ Wv, const float* __restrict__ Wskip,
                            const float* __restrict__ bq, const float* __restrict__ bk,
                            const float* __restrict__ bv, const float* __restrict__ bskip,
                            unsigned short* __restrict__ xb,
                            unsigned short* __restrict__ wcat,
                            float* __restrict__ bcat,
                            int* __restrict__ zbase, int zwords, int N) {
  int t = blockIdx.x * 256 + threadIdx.x;
  int X4 = N * 32;  // x float4 count
  if (t < X4) {
    float4 f = *(const float4*)&x[t * 4];
    ushort4 o;
    o.x = f2bf(f.x); o.y = f2bf(f.y); o.z = f2bf(f.z); o.w = f2bf(f.w);
    *(ushort4*)&xb[t * 4] = o;
  } else if (t < X4 + 1664 * 128) {
    int widx = t - X4;
    if (widx < 3 * 65536) {
      int segi = widx >> 16;       // 0=q 1=k 2=v
      int r = widx & 65535;
      int kk = r >> 9;             // 0..127
      int m = r & 511;             // consecutive -> coalesced source read
      const float* W = (segi == 0) ? Wq : (segi == 1) ? Wk : Wv;
      wcat[(size_t)(segi * 512 + m) * 128 + kk] = f2bf(W[kk * 512 + m]);
    } else {
      int r = widx - 3 * 65536;    // < 16384
      int kk = r >> 7;
      int m = r & 127;
      wcat[(size_t)(1536 + m) * 128 + kk] = f2bf(Wskip[kk * 128 + m]);
    }
  } else if (t < X4 + 1664 * 128 + 1664) {
    int b = t - X4 - 1664 * 128;
    bcat[b] = (b < 512) ? bq[b] : (b < 1024) ? bk[b - 512]
            : (b < 1536) ? bv[b - 1024] : bskip[b - 1536];
  } else if (t < X4 + 1664 * 128 + 1664 + zwords) {
    zbase[t - X4 - 1664 * 128 - 1664] = 0;
  }
}

// ---------------------------------------------------------------------------
// Fused MFMA GEMM + edge histogram.
// [N x 1664] = Xb[N x 128] @ Wt[1664 x 128]^T + bcat
// cols 0-511 -> q bf16; 512-1535 -> k|v fp8; 1536-1663 -> skip fp32.
// Prologue: each block histograms a slice of dst (independent of GEMM work;
// both only depend on prep having zeroed cnt).
// ---------------------------------------------------------------------------
__global__ __launch_bounds__(256) void gemm_mfma_kernel(
    const unsigned short* __restrict__ Xb, const unsigned short* __restrict__ Wt,
    const float* __restrict__ bcat, unsigned short* __restrict__ qb,
    unsigned char* __restrict__ kv8, float* __restrict__ skip,
    const int* __restrict__ dst, int* __restrict__ cnt, int N, int E) {
  const int tid = threadIdx.x;
  // --- histogram slice (no sync needed; outputs independent of GEMM) ---
  {
    int nblk = gridDim.x * gridDim.y;
    int lb = blockIdx.y * gridDim.x + blockIdx.x;
    int per = (E + nblk - 1) / nblk;
    int e0 = lb * per;
    int e1 = min(e0 + per, E);
    for (int e = e0 + tid; e < e1; e += 256) atomicAdd(&cnt[dst[e]], 1);
  }
  // --- GEMM ---
  __shared__ unsigned short Xs[128][72];
  __shared__ unsigned short Ws[128][72];
  const int row0 = blockIdx.x * 128;
  const int col0 = blockIdx.y * 128;
  const int wave = tid >> 6, lane = tid & 63;
  const int wr = (wave >> 1) * 64, wc = (wave & 1) * 64;
  const int l16 = lane & 15, quad = lane >> 4;

  f32x4 acc[4][4] = {};

  for (int kc = 0; kc < 128; kc += 64) {
#pragma unroll
    for (int c = tid; c < 1024; c += 256) {
      int r = c >> 3;
      int k8 = (c & 7) * 8;
      int gr = row0 + r;
      int4 a = {0, 0, 0, 0};
      if (gr < N) a = *(const int4*)&Xb[(size_t)gr * 128 + kc + k8];
      *(int4*)&Xs[r][k8] = a;
      int gc = col0 + r;  // < 1664
      *(int4*)&Ws[r][k8] = *(const int4*)&Wt[(size_t)gc * 128 + kc + k8];
    }
    __syncthreads();
#pragma unroll
    for (int ks = 0; ks < 2; ++ks) {
      int k0 = ks * 32 + quad * 8;
      bf16x8 a[4], b[4];
#pragma unroll
      for (int i = 0; i < 4; ++i) a[i] = *(const bf16x8*)&Xs[wr + i * 16 + l16][k0];
#pragma unroll
      for (int j = 0; j < 4; ++j) b[j] = *(const bf16x8*)&Ws[wc + j * 16 + l16][k0];
#pragma unroll
      for (int i = 0; i < 4; ++i)
#pragma unroll
        for (int j = 0; j < 4; ++j)
          acc[i][j] = __builtin_amdgcn_mfma_f32_16x16x32_bf16(a[i], b[j], acc[i][j], 0, 0, 0);
    }
    __syncthreads();
  }
  const int kind = (col0 < 512) ? 0 : (col0 < 1536) ? 1 : 2;  // block-uniform
#pragma unroll
  for (int i = 0; i < 4; ++i) {
#pragma unroll
    for (int reg = 0; reg < 4; ++reg) {
      int r = row0 + wr + i * 16 + quad * 4 + reg;
      if (r < N) {
#pragma unroll
        for (int j = 0; j < 4; ++j) {
          int cidx = col0 + wc + j * 16 + l16;
          float val = acc[i][j][reg] + bcat[cidx];
          if (kind == 0) {
            qb[(size_t)r * 512 + cidx] = f2bf(val);
          } else if (kind == 1) {
            int pk = __builtin_amdgcn_cvt_pk_fp8_f32(val, val, 0, false);
            kv8[(size_t)r * 1024 + cidx - 512] = (unsigned char)pk;
          } else {
            skip[(size_t)r * 128 + cidx - 1536] = val;
          }
        }
      }
    }
  }
}

// ---------------------------------------------------------------------------
// Cooperative two-level scan (tiny: grid MUST be ceil(N/256) <= 64 blocks).
// Phase 1: block-local exclusive scan; sync; phase 2: block-sum fixup.
// ---------------------------------------------------------------------------
__global__ __launch_bounds__(256) void scan_kernel(
    const int* __restrict__ cnt, int* __restrict__ off, int* __restrict__ bsum,
    int N) {
  cg::grid_group grid = cg::this_grid();
  int tid = threadIdx.x, bx = blockIdx.x, nb = gridDim.x;
  int gt = bx * 256 + tid;
  int lane = tid & 63, w = tid >> 6;
  __shared__ int wsum[4];
  __shared__ int boffs[64];
  {
    int v = (gt < N) ? cnt[gt] : 0;
    int x = v;
#pragma unroll
    for (int d = 1; d < 64; d <<= 1) {
      int y = __shfl_up(x, d);
      if (lane >= d) x += y;
    }
    if (lane == 63) wsum[w] = x;
    __syncthreads();
    int wo = 0;
    for (int jj = 0; jj < w; ++jj) wo += wsum[jj];
    if (gt < N) off[gt] = wo + x - v;
    if (tid == 255) bsum[bx] = wo + x;
  }
  grid.sync();
  if (tid < 64) {
    int v = (tid < nb) ? bsum[tid] : 0;
    int x = v;
#pragma unroll
    for (int d = 1; d < 64; d <<= 1) {
      int y = __shfl_up(x, d);
      if (tid >= d) x += y;
    }
    boffs[tid] = x - v;
    if (bx == 0 && tid == 63) off[N] = x;  // grand total = E
  }
  __syncthreads();
  if (gt < N) off[gt] += boffs[bx];
}

__global__ void scatter_kernel(const int* __restrict__ src, const int* __restrict__ dst,
                               const int* __restrict__ off, int* __restrict__ cur,
                               int* __restrict__ bsrc, int E) {
  int e = blockIdx.x * 256 + threadIdx.x;
  if (e < E) {
    int d = dst[e];
    int p = off[d] + atomicAdd(&cur[d], 1);
    bsrc[p] = src[e];
  }
}

// ---------------------------------------------------------------------------
// Attention, head-phased, edge-per-16-lane-group.
// Lane = g*16 + j; group g handles edge slot idx+g; lane j covers cols
// j*8..j*8+7 for both the k-dot and the v-accumulate (v = k addr + 512).
// Cross-group butterfly only at loop end. No max-shift (|alpha| bounded).
// ---------------------------------------------------------------------------
__global__ __launch_bounds__(256) void attn_kernel(
    const unsigned short* __restrict__ qb, const unsigned char* __restrict__ kv8,
    const int* __restrict__ off, const int* __restrict__ bsrc,
    unsigned* __restrict__ oh, int N, int nper) {
  int bx = blockIdx.x;
  int head = bx / nper;
  int tid = threadIdx.x;
  int w = tid >> 6, lane = tid & 63;
  int node = (bx - head * nper) * 4 + w;
  if (node >= N) return;
  int g = lane >> 4, j = lane & 15;

  const float qscale = 0.08838834764831845f * 1.4426950408889634f;  // /sqrt(128)*log2e
  int4 qi = *(const int4*)(qb + (size_t)node * 512 + head * 128 + j * 8);
  float qf0 = bflo(qi.x) * qscale, qf1 = bfhi(qi.x) * qscale;
  float qf2 = bflo(qi.y) * qscale, qf3 = bfhi(qi.y) * qscale;
  float qf4 = bflo(qi.z) * qscale, qf5 = bfhi(qi.z) * qscale;
  float qf6 = bflo(qi.w) * qscale, qf7 = bfhi(qi.w) * qscale;

  const unsigned char* kb = kv8 + head * 128 + j * 8;
  int beg = off[node], end = off[node + 1];
  float lsum = 0.f;
  float o0 = 0.f, o1 = 0.f, o2 = 0.f, o3 = 0.f;
  float o4 = 0.f, o5 = 0.f, o6 = 0.f, o7 = 0.f;

  for (int idx = beg; idx < end; idx += 4) {
    int rem = end - idx;
    int e = bsrc[idx + ((g < rem) ? g : 0)];
    const unsigned char* kp = kb + (size_t)e * 1024;
    uint2 kw = *(const uint2*)kp;
    uint2 vw = *(const uint2*)(kp + 512);
    f32x2 k01 = __builtin_amdgcn_cvt_pk_f32_fp8(kw.x, false);
    f32x2 k23 = __builtin_amdgcn_cvt_pk_f32_fp8(kw.x, true);
    f32x2 k45 = __builtin_amdgcn_cvt_pk_f32_fp8(kw.y, false);
    f32x2 k67 = __builtin_amdgcn_cvt_pk_f32_fp8(kw.y, true);
    float p = qf0 * k01.x + qf1 * k01.y + qf2 * k23.x + qf3 * k23.y +
              qf4 * k45.x + qf5 * k45.y + qf6 * k67.x + qf7 * k67.y;
    p += __shfl_xor(p, 1);
    p += __shfl_xor(p, 2);
    p += __shfl_xor(p, 4);
    p += __shfl_xor(p, 8);
    float a = (g < rem) ? p : -1e30f;
    float wgt = exp2f(a);  // exp2(-1e30) = 0 for inactive slots
    f32x2 v01 = __builtin_amdgcn_cvt_pk_f32_fp8(vw.x, false);
    f32x2 v23 = __builtin_amdgcn_cvt_pk_f32_fp8(vw.x, true);
    f32x2 v45 = __builtin_amdgcn_cvt_pk_f32_fp8(vw.y, false);
    f32x2 v67 = __builtin_amdgcn_cvt_pk_f32_fp8(vw.y, true);
    lsum += wgt;
    o0 += wgt * v01.x; o1 += wgt * v01.y;
    o2 += wgt * v23.x; o3 += wgt * v23.y;
    o4 += wgt * v45.x; o5 += wgt * v45.y;
    o6 += wgt * v67.x; o7 += wgt * v67.y;
  }
  // cross-group butterfly (4 groups -> full sums on every lane)
  o0 += __shfl_xor(o0, 16); o0 += __shfl_xor(o0, 32);
  o1 += __shfl_xor(o1, 16); o1 += __shfl_xor(o1, 32);
  o2 += __shfl_xor(o2, 16); o2 += __shfl_xor(o2, 32);
  o3 += __shfl_xor(o3, 16); o3 += __shfl_xor(o3, 32);
  o4 += __shfl_xor(o4, 16); o4 += __shfl_xor(o4, 32);
  o5 += __shfl_xor(o5, 16); o5 += __shfl_xor(o5, 32);
  o6 += __shfl_xor(o6, 16); o6 += __shfl_xor(o6, 32);
  o7 += __shfl_xor(o7, 16); o7 += __shfl_xor(o7, 32);
  lsum += __shfl_xor(lsum, 16); lsum += __shfl_xor(lsum, 32);
  float inv = 1.f / (lsum + 1e-16f);
  if (g == 0) {
    unsigned d0 = (unsigned)f2bf(o0 * inv) | ((unsigned)f2bf(o1 * inv) << 16);
    unsigned d1 = (unsigned)f2bf(o2 * inv) | ((unsigned)f2bf(o3 * inv) << 16);
    unsigned d2 = (unsigned)f2bf(o4 * inv) | ((unsigned)f2bf(o5 * inv) << 16);
    unsigned d3 = (unsigned)f2bf(o6 * inv) | ((unsigned)f2bf(o7 * inv) << 16);
    int4 st; st.x = (int)d0; st.y = (int)d1; st.z = (int)d2; st.w = (int)d3;
    *(int4*)(oh + ((size_t)head * N + node) * 64 + j * 4) = st;
  }
}

// ---------------------------------------------------------------------------
// Cooperative combine+stats+final. Grid MUST be CF_BLOCKS x 256.
// 640 blocks * 4 waves * CF_ROWS(4) = 10240 rows >= N.
// ---------------------------------------------------------------------------
#define CF_BLOCKS 640
#define CF_ROWS 4
__global__ __launch_bounds__(256) void combine_final_kernel(
    const unsigned* __restrict__ oh, const float* __restrict__ skip,
    const float* __restrict__ Wbeta, const float* __restrict__ gnw,
    const float* __restrict__ gnb, const float* __restrict__ gnms,
    const float* __restrict__ x, float* __restrict__ y,
    float* __restrict__ colsum, float* __restrict__ colsq, int N, float invN) {
  cg::grid_group grid = cg::this_grid();
  int tid = threadIdx.x;
  int lane = tid & 63, w = tid >> 6;
  int step = gridDim.x * 4;
  int base = blockIdx.x * 4 + w;
  float2 wb0 = *(const float2*)&Wbeta[lane * 2];
  float2 wb1 = *(const float2*)&Wbeta[128 + lane * 2];
  float2 wb2 = *(const float2*)&Wbeta[256 + lane * 2];
  float ro0[CF_ROWS], ro1[CF_ROWS];
  float cs0 = 0.f, cq0 = 0.f, cs1 = 0.f, cq1 = 0.f;
#pragma unroll
  for (int r = 0; r < CF_ROWS; ++r) {
    int n = base + r * step;
    ro0[r] = 0.f; ro1[r] = 0.f;
    if (n < N) {
      unsigned h0 = oh[((size_t)0 * N + n) * 64 + lane];
      unsigned h1 = oh[((size_t)1 * N + n) * 64 + lane];
      unsigned h2 = oh[((size_t)2 * N + n) * 64 + lane];
      unsigned h3 = oh[((size_t)3 * N + n) * 64 + lane];
      float a0 = 0.25f * (bflo(h0) + bflo(h1) + bflo(h2) + bflo(h3));
      float a1 = 0.25f * (bfhi(h0) + bfhi(h1) + bfhi(h2) + bfhi(h3));
      float2 s = *(const float2*)&skip[(size_t)n * 128 + lane * 2];
      float p = a0 * wb0.x + s.x * wb1.x + (a0 - s.x) * wb2.x +
                a1 * wb0.y + s.y * wb1.y + (a1 - s.y) * wb2.y;
#pragma unroll
      for (int dmask = 1; dmask < 64; dmask <<= 1) p += __shfl_xor(p, dmask);
      float beta = 1.f / (1.f + __expf(-p));
      float oo0 = beta * s.x + (1.f - beta) * a0;
      float oo1 = beta * s.y + (1.f - beta) * a1;
      ro0[r] = oo0; ro1[r] = oo1;
      cs0 += oo0; cq0 += oo0 * oo0;
      cs1 += oo1; cq1 += oo1 * oo1;
    }
  }
  int c = lane * 2;
  atomicAdd(&colsum[c], cs0);
  atomicAdd(&colsum[c + 1], cs1);
  atomicAdd(&colsq[c], cq0);
  atomicAdd(&colsq[c + 1], cq1);
  grid.sync();
  // phase 2: stats + groupnorm + GELU + residual
  float2 cs = *(const float2*)&colsum[c];
  float2 cq = *(const float2*)&colsq[c];
  float2 gw = *(const float2*)&gnw[c];
  float2 gb = *(const float2*)&gnb[c];
  float2 gs = *(const float2*)&gnms[c];
  float mean0 = cs.x * invN, mean1 = cs.y * invN;
  float var0 = cq.x * invN - mean0 * mean0 * gs.x * (2.f - gs.x);
  float var1 = cq.y * invN - mean1 * mean1 * gs.y * (2.f - gs.y);
  float mul0 = gw.x / sqrtf(var0 + 1e-5f);
  float mul1 = gw.y / sqrtf(var1 + 1e-5f);
  float sub0 = gs.x * mean0, sub1 = gs.y * mean1;
#pragma unroll
  for (int r = 0; r < CF_ROWS; ++r) {
    int n = base + r * step;
    if (n < N) {
      float t0 = (ro0[r] - sub0) * mul0 + gb.x;
      float t1 = (ro1[r] - sub1) * mul1 + gb.y;
      float g0 = 0.5f * t0 * (1.f + erff(t0 * 0.70710678118654752f));
      float g1 = 0.5f * t1 * (1.f + erff(t1 * 0.70710678118654752f));
      float2 xx = *(const float2*)&x[(size_t)n * 128 + c];
      float2 rr; rr.x = g0 + xx.x; rr.y = g1 + xx.y;
      *(float2*)&y[(size_t)n * 128 + c] = rr;
    }
  }
}

extern "C" void kernel_launch(void* const* d_in, const int* in_sizes, int n_in,
                              void* d_out, int out_size, void* d_ws, size_t ws_size,
                              hipStream_t stream) {
  const float* x     = (const float*)d_in[0];
  const int*   ei    = (const int*)d_in[1];
  const float* Wq    = (const float*)d_in[2];
  const float* bq    = (const float*)d_in[3];
  const float* Wk    = (const float*)d_in[4];
  const float* bk    = (const float*)d_in[5];
  const float* Wv    = (const float*)d_in[6];
  const float* bv    = (const float*)d_in[7];
  const float* Wskip = (const float*)d_in[8];
  const float* bskip = (const float*)d_in[9];
  const float* Wbeta = (const float*)d_in[10];
  const float* gnw   = (const float*)d_in[11];
  const float* gnb   = (const float*)d_in[12];
  const float* gnms  = (const float*)d_in[13];

  const int N = in_sizes[0] / D_DIM;   // 10000
  const int E = in_sizes[1] / 2;       // 160000
  const int* src = ei;
  const int* dst = ei + E;

  // workspace carve-up (alias: xb over oh — disjoint lifetimes)
  char* p = (char*)d_ws;
  unsigned short* qb  = (unsigned short*)p; p += (size_t)N * 512 * 2;     // q bf16
  unsigned char*  kv8 = (unsigned char*)p;  p += (size_t)N * 1024;        // k|v fp8
  unsigned*       oh  = (unsigned*)p;       p += (size_t)4 * N * 64 * 4;  // per-head out bf16x2
  float*          skip = (float*)p;         p += (size_t)N * 128 * 4;
  // contiguous zero region: cnt | cur | colsum | colsq
  int*   cnt    = (int*)p;   p += (size_t)N * 4;
  int*   cur    = (int*)p;   p += (size_t)N * 4;
  float* colsum = (float*)p; p += 128 * 4;
  float* colsq  = (float*)p; p += 128 * 4;
  int zwords = 2 * N + 256;
  int* off    = (int*)p;   p += (size_t)(N + 1) * 4;
  int* bsum   = (int*)p;   p += 64 * 4;
  int* bsrc   = (int*)p;   p += (size_t)E * 4;
  unsigned short* wcat = (unsigned short*)p; p += (size_t)1664 * 128 * 2;
  float* bcat = (float*)p; p += 1664 * 4;
  unsigned short* xb = (unsigned short*)oh;  // alias: xb dead before oh written

  // 1) prep (casts + weight transpose + zeroing)
  int prepTotal = N * 32 + 1664 * 128 + 1664 + zwords;
  prep_kernel<<<(prepTotal + 255) / 256, 256, 0, stream>>>(
      x, Wq, Wk, Wv, Wskip, bq, bk, bv, bskip, xb, wcat, bcat, cnt, zwords, N);

  // 2) fused QKV+skip GEMM + edge histogram
  const int rowBlocks = (N + 127) / 128;  // 79
  gemm_mfma_kernel<<<dim3(rowBlocks, 13), 256, 0, stream>>>(
      xb, wcat, bcat, qb, kv8, skip, dst, cnt, N, E);

  // 3) cooperative two-level scan (tiny grid: 40 blocks)
  {
    int nBlocks = (N + 255) / 256;  // 40 <= 64
    int n_ = N;
    void* args[] = {(void*)&cnt, (void*)&off, (void*)&bsum, (void*)&n_};
    hipLaunchCooperativeKernel((void*)scan_kernel, dim3(nBlocks), dim3(256), args, 0, stream);
  }

  // 4) scatter (wide grid)
  int eBlocks = (E + 255) / 256;  // 625
  scatter_kernel<<<eBlocks, 256, 0, stream>>>(src, dst, off, cur, bsrc, E);

  // 5) head-phased attention
  int nper = (N + 3) / 4;  // 2500 node-quads per head
  attn_kernel<<<nper * 4, 256, 0, stream>>>(qb, kv8, off, bsrc, oh, N, nper);

  // 6) cooperative combine + stats + finalize (640 blocks: 2.5 blocks/CU)
  {
    int n_ = N;
    float invN = 1.f / (float)N;
    float* yp = (float*)d_out;
    void* args[] = {(void*)&oh, (void*)&skip, (void*)&Wbeta, (void*)&gnw,
                    (void*)&gnb, (void*)&gnms, (void*)&x, (void*)&yp,
                    (void*)&colsum, (void*)&colsq, (void*)&n_, (void*)&invN};
    hipLaunchCooperativeKernel((void*)combine_final_kernel, dim3(CF_BLOCKS), dim3(256), args, 0, stream);
  }
}

// Round 8
// 229.009 us; speedup vs baseline: 1.6663x; 1.6663x over previous
//
#include <hip/hip_runtime.h>
#include <hip/hip_bf16.h>
#include <math.h>

// Problem constants: N=10000, E=160000, D=128, H=4, C=128, HC=512
#define D_DIM 128
#define HC_DIM 512

typedef __attribute__((ext_vector_type(8))) short bf16x8;
typedef __attribute__((ext_vector_type(4))) float f32x4;
typedef __attribute__((ext_vector_type(2))) float f32x2;

static __device__ __forceinline__ unsigned short f2bf(float f) {
  unsigned u = __float_as_uint(f);
  unsigned r = (u + 0x7fffu + ((u >> 16) & 1u)) >> 16;  // RNE
  return (unsigned short)r;
}
static __device__ __forceinline__ float bflo(unsigned u) {
  return __uint_as_float(u << 16);
}
static __device__ __forceinline__ float bfhi(unsigned u) {
  return __uint_as_float(u & 0xffff0000u);
}

// ---------------------------------------------------------------------------
// prep: cast x -> bf16; build Wt [1664][128] bf16 (coalesced source reads);
// bcat[1664]; zero counter region (cnt|cur|colsum|colsq).
// ---------------------------------------------------------------------------
__global__ void prep_kernel(const float* __restrict__ x,
                            const float* __restrict__ Wq, const float* __restrict__ Wk,
                            const float* __restrict__ Wv, const float* __restrict__ Wskip,
                            const float* __restrict__ bq, const float* __restrict__ bk,
                            const float* __restrict__ bv, const float* __restrict__ bskip,
                            unsigned short* __restrict__ xb,
                            unsigned short* __restrict__ wcat,
                            float* __restrict__ bcat,
                            int* __restrict__ zbase, int zwords, int N) {
  int t = blockIdx.x * 256 + threadIdx.x;
  int X4 = N * 32;  // x float4 count
  if (t < X4) {
    float4 f = *(const float4*)&x[t * 4];
    ushort4 o;
    o.x = f2bf(f.x); o.y = f2bf(f.y); o.z = f2bf(f.z); o.w = f2bf(f.w);
    *(ushort4*)&xb[t * 4] = o;
  } else if (t < X4 + 1664 * 128) {
    int widx = t - X4;
    if (widx < 3 * 65536) {
      int segi = widx >> 16;       // 0=q 1=k 2=v
      int r = widx & 65535;
      int kk = r >> 9;             // 0..127
      int m = r & 511;             // consecutive -> coalesced source read
      const float* W = (segi == 0) ? Wq : (segi == 1) ? Wk : Wv;
      wcat[(size_t)(segi * 512 + m) * 128 + kk] = f2bf(W[kk * 512 + m]);
    } else {
      int r = widx - 3 * 65536;    // < 16384
      int kk = r >> 7;
      int m = r & 127;
      wcat[(size_t)(1536 + m) * 128 + kk] = f2bf(Wskip[kk * 128 + m]);
    }
  } else if (t < X4 + 1664 * 128 + 1664) {
    int b = t - X4 - 1664 * 128;
    bcat[b] = (b < 512) ? bq[b] : (b < 1024) ? bk[b - 512]
            : (b < 1536) ? bv[b - 1024] : bskip[b - 1536];
  } else if (t < X4 + 1664 * 128 + 1664 + zwords) {
    zbase[t - X4 - 1664 * 128 - 1664] = 0;
  }
}

// ---------------------------------------------------------------------------
// Fused MFMA GEMM + edge histogram.
// [N x 1664] = Xb[N x 128] @ Wt[1664 x 128]^T + bcat
// cols 0-511 -> q bf16; 512-1535 -> k|v fp8; 1536-1663 -> skip fp32.
// ---------------------------------------------------------------------------
__global__ __launch_bounds__(256) void gemm_mfma_kernel(
    const unsigned short* __restrict__ Xb, const unsigned short* __restrict__ Wt,
    const float* __restrict__ bcat, unsigned short* __restrict__ qb,
    unsigned char* __restrict__ kv8, float* __restrict__ skip,
    const int* __restrict__ dst, int* __restrict__ cnt, int N, int E) {
  const int tid = threadIdx.x;
  // --- histogram slice (independent of GEMM work) ---
  {
    int nblk = gridDim.x * gridDim.y;
    int lb = blockIdx.y * gridDim.x + blockIdx.x;
    int per = (E + nblk - 1) / nblk;
    int e0 = lb * per;
    int e1 = min(e0 + per, E);
    for (int e = e0 + tid; e < e1; e += 256) atomicAdd(&cnt[dst[e]], 1);
  }
  // --- GEMM ---
  __shared__ unsigned short Xs[128][72];
  __shared__ unsigned short Ws[128][72];
  const int row0 = blockIdx.x * 128;
  const int col0 = blockIdx.y * 128;
  const int wave = tid >> 6, lane = tid & 63;
  const int wr = (wave >> 1) * 64, wc = (wave & 1) * 64;
  const int l16 = lane & 15, quad = lane >> 4;

  f32x4 acc[4][4] = {};

  for (int kc = 0; kc < 128; kc += 64) {
#pragma unroll
    for (int c = tid; c < 1024; c += 256) {
      int r = c >> 3;
      int k8 = (c & 7) * 8;
      int gr = row0 + r;
      int4 a = {0, 0, 0, 0};
      if (gr < N) a = *(const int4*)&Xb[(size_t)gr * 128 + kc + k8];
      *(int4*)&Xs[r][k8] = a;
      int gc = col0 + r;  // < 1664
      *(int4*)&Ws[r][k8] = *(const int4*)&Wt[(size_t)gc * 128 + kc + k8];
    }
    __syncthreads();
#pragma unroll
    for (int ks = 0; ks < 2; ++ks) {
      int k0 = ks * 32 + quad * 8;
      bf16x8 a[4], b[4];
#pragma unroll
      for (int i = 0; i < 4; ++i) a[i] = *(const bf16x8*)&Xs[wr + i * 16 + l16][k0];
#pragma unroll
      for (int j = 0; j < 4; ++j) b[j] = *(const bf16x8*)&Ws[wc + j * 16 + l16][k0];
#pragma unroll
      for (int i = 0; i < 4; ++i)
#pragma unroll
        for (int j = 0; j < 4; ++j)
          acc[i][j] = __builtin_amdgcn_mfma_f32_16x16x32_bf16(a[i], b[j], acc[i][j], 0, 0, 0);
    }
    __syncthreads();
  }
  const int kind = (col0 < 512) ? 0 : (col0 < 1536) ? 1 : 2;  // block-uniform
#pragma unroll
  for (int i = 0; i < 4; ++i) {
#pragma unroll
    for (int reg = 0; reg < 4; ++reg) {
      int r = row0 + wr + i * 16 + quad * 4 + reg;
      if (r < N) {
#pragma unroll
        for (int j = 0; j < 4; ++j) {
          int cidx = col0 + wc + j * 16 + l16;
          float val = acc[i][j][reg] + bcat[cidx];
          if (kind == 0) {
            qb[(size_t)r * 512 + cidx] = f2bf(val);
          } else if (kind == 1) {
            int pk = __builtin_amdgcn_cvt_pk_fp8_f32(val, val, 0, false);
            kv8[(size_t)r * 1024 + cidx - 512] = (unsigned char)pk;
          } else {
            skip[(size_t)r * 128 + cidx - 1536] = val;
          }
        }
      }
    }
  }
}

// ---------------------------------------------------------------------------
// Two-level scan, plain kernels (no grid.sync!)
// ---------------------------------------------------------------------------
__global__ __launch_bounds__(256) void scan1_kernel(const int* __restrict__ cnt,
                                                    int* __restrict__ off,
                                                    int* __restrict__ bsum, int n) {
  __shared__ int wsum[4];
  int tid = threadIdx.x;
  int i = blockIdx.x * 256 + tid;
  int lane = tid & 63, w = tid >> 6;
  int v = (i < n) ? cnt[i] : 0;
  int x = v;
#pragma unroll
  for (int d = 1; d < 64; d <<= 1) {
    int y = __shfl_up(x, d);
    if (lane >= d) x += y;
  }
  if (lane == 63) wsum[w] = x;
  __syncthreads();
  int wo = 0;
  for (int j = 0; j < w; ++j) wo += wsum[j];
  if (i < n) off[i] = wo + x - v;
  if (tid == 255) bsum[blockIdx.x] = wo + x;
}

// each block redundantly scans bsum (nb <= 64), fixes its slice
__global__ __launch_bounds__(256) void scan23_kernel(int* __restrict__ off,
                                                     const int* __restrict__ bsum,
                                                     int nb, int n) {
  __shared__ int boffs[64];
  int tid = threadIdx.x;
  if (tid < 64) {
    int v = (tid < nb) ? bsum[tid] : 0;
    int x = v;
#pragma unroll
    for (int d = 1; d < 64; d <<= 1) {
      int y = __shfl_up(x, d);
      if (tid >= d) x += y;
    }
    boffs[tid] = x - v;
    if (tid == 63 && blockIdx.x == 0) off[n] = x;  // grand total
  }
  __syncthreads();
  int i = blockIdx.x * 256 + tid;
  if (i < n) off[i] += boffs[blockIdx.x];
}

__global__ void scatter_kernel(const int* __restrict__ src, const int* __restrict__ dst,
                               const int* __restrict__ off, int* __restrict__ cur,
                               int* __restrict__ bsrc, int E) {
  int e = blockIdx.x * 256 + threadIdx.x;
  if (e < E) {
    int d = dst[e];
    int p = off[d] + atomicAdd(&cur[d], 1);
    bsrc[p] = src[e];
  }
}

// ---------------------------------------------------------------------------
// Attention, head-phased, edge-per-16-lane-group (see round 6 notes).
// ---------------------------------------------------------------------------
__global__ __launch_bounds__(256) void attn_kernel(
    const unsigned short* __restrict__ qb, const unsigned char* __restrict__ kv8,
    const int* __restrict__ off, const int* __restrict__ bsrc,
    unsigned* __restrict__ oh, int N, int nper) {
  int bx = blockIdx.x;
  int head = bx / nper;
  int tid = threadIdx.x;
  int w = tid >> 6, lane = tid & 63;
  int node = (bx - head * nper) * 4 + w;
  if (node >= N) return;
  int g = lane >> 4, j = lane & 15;

  const float qscale = 0.08838834764831845f * 1.4426950408889634f;  // /sqrt(128)*log2e
  int4 qi = *(const int4*)(qb + (size_t)node * 512 + head * 128 + j * 8);
  float qf0 = bflo(qi.x) * qscale, qf1 = bfhi(qi.x) * qscale;
  float qf2 = bflo(qi.y) * qscale, qf3 = bfhi(qi.y) * qscale;
  float qf4 = bflo(qi.z) * qscale, qf5 = bfhi(qi.z) * qscale;
  float qf6 = bflo(qi.w) * qscale, qf7 = bfhi(qi.w) * qscale;

  const unsigned char* kb = kv8 + head * 128 + j * 8;
  int beg = off[node], end = off[node + 1];
  float lsum = 0.f;
  float o0 = 0.f, o1 = 0.f, o2 = 0.f, o3 = 0.f;
  float o4 = 0.f, o5 = 0.f, o6 = 0.f, o7 = 0.f;

  for (int idx = beg; idx < end; idx += 4) {
    int rem = end - idx;
    int e = bsrc[idx + ((g < rem) ? g : 0)];
    const unsigned char* kp = kb + (size_t)e * 1024;
    uint2 kw = *(const uint2*)kp;
    uint2 vw = *(const uint2*)(kp + 512);
    f32x2 k01 = __builtin_amdgcn_cvt_pk_f32_fp8(kw.x, false);
    f32x2 k23 = __builtin_amdgcn_cvt_pk_f32_fp8(kw.x, true);
    f32x2 k45 = __builtin_amdgcn_cvt_pk_f32_fp8(kw.y, false);
    f32x2 k67 = __builtin_amdgcn_cvt_pk_f32_fp8(kw.y, true);
    float p = qf0 * k01.x + qf1 * k01.y + qf2 * k23.x + qf3 * k23.y +
              qf4 * k45.x + qf5 * k45.y + qf6 * k67.x + qf7 * k67.y;
    p += __shfl_xor(p, 1);
    p += __shfl_xor(p, 2);
    p += __shfl_xor(p, 4);
    p += __shfl_xor(p, 8);
    float a = (g < rem) ? p : -1e30f;
    float wgt = exp2f(a);  // exp2(-1e30) = 0 for inactive slots
    f32x2 v01 = __builtin_amdgcn_cvt_pk_f32_fp8(vw.x, false);
    f32x2 v23 = __builtin_amdgcn_cvt_pk_f32_fp8(vw.x, true);
    f32x2 v45 = __builtin_amdgcn_cvt_pk_f32_fp8(vw.y, false);
    f32x2 v67 = __builtin_amdgcn_cvt_pk_f32_fp8(vw.y, true);
    lsum += wgt;
    o0 += wgt * v01.x; o1 += wgt * v01.y;
    o2 += wgt * v23.x; o3 += wgt * v23.y;
    o4 += wgt * v45.x; o5 += wgt * v45.y;
    o6 += wgt * v67.x; o7 += wgt * v67.y;
  }
  // cross-group butterfly (4 groups -> full sums on every lane)
  o0 += __shfl_xor(o0, 16); o0 += __shfl_xor(o0, 32);
  o1 += __shfl_xor(o1, 16); o1 += __shfl_xor(o1, 32);
  o2 += __shfl_xor(o2, 16); o2 += __shfl_xor(o2, 32);
  o3 += __shfl_xor(o3, 16); o3 += __shfl_xor(o3, 32);
  o4 += __shfl_xor(o4, 16); o4 += __shfl_xor(o4, 32);
  o5 += __shfl_xor(o5, 16); o5 += __shfl_xor(o5, 32);
  o6 += __shfl_xor(o6, 16); o6 += __shfl_xor(o6, 32);
  o7 += __shfl_xor(o7, 16); o7 += __shfl_xor(o7, 32);
  lsum += __shfl_xor(lsum, 16); lsum += __shfl_xor(lsum, 32);
  float inv = 1.f / (lsum + 1e-16f);
  if (g == 0) {
    unsigned d0 = (unsigned)f2bf(o0 * inv) | ((unsigned)f2bf(o1 * inv) << 16);
    unsigned d1 = (unsigned)f2bf(o2 * inv) | ((unsigned)f2bf(o3 * inv) << 16);
    unsigned d2 = (unsigned)f2bf(o4 * inv) | ((unsigned)f2bf(o5 * inv) << 16);
    unsigned d3 = (unsigned)f2bf(o6 * inv) | ((unsigned)f2bf(o7 * inv) << 16);
    int4 st; st.x = (int)d0; st.y = (int)d1; st.z = (int)d2; st.w = (int)d3;
    *(int4*)(oh + ((size_t)head * N + node) * 64 + j * 4) = st;
  }
}

// ---------------------------------------------------------------------------
// combine: beta gate + head-mean + out2 + column sums.
// 625 blocks x 256; wave wid=bx*4+w handles rows wid + k*2500, k=0..3.
// Block-level LDS reduction -> 1 atomic per block per column.
// ---------------------------------------------------------------------------
__global__ __launch_bounds__(256) void combine_kernel(
    const unsigned* __restrict__ oh, const float* __restrict__ skip,
    const float* __restrict__ Wbeta, float* __restrict__ out2,
    float* __restrict__ colsum, float* __restrict__ colsq, int N) {
  int tid = threadIdx.x;
  int lane = tid & 63, w = tid >> 6;
  int wid = blockIdx.x * 4 + w;  // 0..2499
  float2 wb0 = *(const float2*)&Wbeta[lane * 2];
  float2 wb1 = *(const float2*)&Wbeta[128 + lane * 2];
  float2 wb2 = *(const float2*)&Wbeta[256 + lane * 2];
  float cs0 = 0.f, cq0 = 0.f, cs1 = 0.f, cq1 = 0.f;
#pragma unroll
  for (int k = 0; k < 4; ++k) {
    int n = wid + k * 2500;
    if (n < N) {
      unsigned h0 = oh[((size_t)0 * N + n) * 64 + lane];
      unsigned h1 = oh[((size_t)1 * N + n) * 64 + lane];
      unsigned h2 = oh[((size_t)2 * N + n) * 64 + lane];
      unsigned h3 = oh[((size_t)3 * N + n) * 64 + lane];
      float a0 = 0.25f * (bflo(h0) + bflo(h1) + bflo(h2) + bflo(h3));
      float a1 = 0.25f * (bfhi(h0) + bfhi(h1) + bfhi(h2) + bfhi(h3));
      float2 s = *(const float2*)&skip[(size_t)n * 128 + lane * 2];
      float p = a0 * wb0.x + s.x * wb1.x + (a0 - s.x) * wb2.x +
                a1 * wb0.y + s.y * wb1.y + (a1 - s.y) * wb2.y;
#pragma unroll
      for (int dmask = 1; dmask < 64; dmask <<= 1) p += __shfl_xor(p, dmask);
      float beta = 1.f / (1.f + __expf(-p));
      float o0 = beta * s.x + (1.f - beta) * a0;
      float o1 = beta * s.y + (1.f - beta) * a1;
      float2 ov; ov.x = o0; ov.y = o1;
      *(float2*)&out2[(size_t)n * 128 + lane * 2] = ov;
      cs0 += o0; cq0 += o0 * o0;
      cs1 += o1; cq1 += o1 * o1;
    }
  }
  // block-level reduction: wave w writes partials, wave 0 sums + atomics
  __shared__ float red[4][256];
  red[w][lane * 2] = cs0;
  red[w][lane * 2 + 1] = cs1;
  red[w][lane * 2 + 128] = 0.f;  // unused pad to keep indexing simple
  __syncthreads();
  __shared__ float redq[4][128];
  redq[w][lane * 2] = cq0;
  redq[w][lane * 2 + 1] = cq1;
  __syncthreads();
  if (w == 0) {
    int c = lane * 2;
    float s0 = red[0][c] + red[1][c] + red[2][c] + red[3][c];
    float s1 = red[0][c + 1] + red[1][c + 1] + red[2][c + 1] + red[3][c + 1];
    float q0 = redq[0][c] + redq[1][c] + redq[2][c] + redq[3][c];
    float q1 = redq[0][c + 1] + redq[1][c + 1] + redq[2][c + 1] + redq[3][c + 1];
    atomicAdd(&colsum[c], s0);
    atomicAdd(&colsum[c + 1], s1);
    atomicAdd(&colsq[c], q0);
    atomicAdd(&colsq[c + 1], q1);
  }
}

// ---------------------------------------------------------------------------
// finalize: inline redundant column stats + groupnorm + exact GELU + residual
// ---------------------------------------------------------------------------
__global__ void final_kernel(const float* __restrict__ out2,
                             const float* __restrict__ colsum,
                             const float* __restrict__ colsq,
                             const float* __restrict__ gnw,
                             const float* __restrict__ gnb,
                             const float* __restrict__ gnms,
                             const float* __restrict__ x,
                             float* __restrict__ y, int total2, float invN) {
  int i = blockIdx.x * 256 + threadIdx.x;
  if (i < total2) {
    int c = (i & 63) * 2;
    float2 cs = *(const float2*)&colsum[c];
    float2 cq = *(const float2*)&colsq[c];
    float2 gw = *(const float2*)&gnw[c];
    float2 gb = *(const float2*)&gnb[c];
    float2 gs = *(const float2*)&gnms[c];
    float mean0 = cs.x * invN, mean1 = cs.y * invN;
    float var0 = cq.x * invN - mean0 * mean0 * gs.x * (2.f - gs.x);
    float var1 = cq.y * invN - mean1 * mean1 * gs.y * (2.f - gs.y);
    float mul0 = gw.x / sqrtf(var0 + 1e-5f);
    float mul1 = gw.y / sqrtf(var1 + 1e-5f);
    float2 o = *(const float2*)&out2[i * 2];
    float2 xx = *(const float2*)&x[i * 2];
    float t0 = (o.x - gs.x * mean0) * mul0 + gb.x;
    float t1 = (o.y - gs.y * mean1) * mul1 + gb.y;
    float g0 = 0.5f * t0 * (1.f + erff(t0 * 0.70710678118654752f));
    float g1 = 0.5f * t1 * (1.f + erff(t1 * 0.70710678118654752f));
    float2 r; r.x = g0 + xx.x; r.y = g1 + xx.y;
    *(float2*)&y[i * 2] = r;
  }
}

extern "C" void kernel_launch(void* const* d_in, const int* in_sizes, int n_in,
                              void* d_out, int out_size, void* d_ws, size_t ws_size,
                              hipStream_t stream) {
  const float* x     = (const float*)d_in[0];
  const int*   ei    = (const int*)d_in[1];
  const float* Wq    = (const float*)d_in[2];
  const float* bq    = (const float*)d_in[3];
  const float* Wk    = (const float*)d_in[4];
  const float* bk    = (const float*)d_in[5];
  const float* Wv    = (const float*)d_in[6];
  const float* bv    = (const float*)d_in[7];
  const float* Wskip = (const float*)d_in[8];
  const float* bskip = (const float*)d_in[9];
  const float* Wbeta = (const float*)d_in[10];
  const float* gnw   = (const float*)d_in[11];
  const float* gnb   = (const float*)d_in[12];
  const float* gnms  = (const float*)d_in[13];

  const int N = in_sizes[0] / D_DIM;   // 10000
  const int E = in_sizes[1] / 2;       // 160000
  const int* src = ei;
  const int* dst = ei + E;

  // workspace carve-up (aliases: xb over oh; out2 over qb — disjoint lifetimes)
  char* p = (char*)d_ws;
  unsigned short* qb  = (unsigned short*)p; p += (size_t)N * 512 * 2;     // q bf16
  unsigned char*  kv8 = (unsigned char*)p;  p += (size_t)N * 1024;        // k|v fp8
  unsigned*       oh  = (unsigned*)p;       p += (size_t)4 * N * 64 * 4;  // per-head out bf16x2
  float*          skip = (float*)p;         p += (size_t)N * 128 * 4;
  float*          out2 = (float*)p;         p += (size_t)N * 128 * 4;
  // contiguous zero region: cnt | cur | colsum | colsq
  int*   cnt    = (int*)p;   p += (size_t)N * 4;
  int*   cur    = (int*)p;   p += (size_t)N * 4;
  float* colsum = (float*)p; p += 128 * 4;
  float* colsq  = (float*)p; p += 128 * 4;
  int zwords = 2 * N + 256;
  int* off    = (int*)p;   p += (size_t)(N + 1) * 4;
  int* bsum   = (int*)p;   p += 64 * 4;
  int* bsrc   = (int*)p;   p += (size_t)E * 4;
  unsigned short* wcat = (unsigned short*)p; p += (size_t)1664 * 128 * 2;
  float* bcat = (float*)p; p += 1664 * 4;
  unsigned short* xb = (unsigned short*)oh;  // alias: xb dead before oh written

  // 1) prep (casts + weight transpose + zeroing)
  int prepTotal = N * 32 + 1664 * 128 + 1664 + zwords;
  prep_kernel<<<(prepTotal + 255) / 256, 256, 0, stream>>>(
      x, Wq, Wk, Wv, Wskip, bq, bk, bv, bskip, xb, wcat, bcat, cnt, zwords, N);

  // 2) fused QKV+skip GEMM + edge histogram
  const int rowBlocks = (N + 127) / 128;  // 79
  gemm_mfma_kernel<<<dim3(rowBlocks, 13), 256, 0, stream>>>(
      xb, wcat, bcat, qb, kv8, skip, dst, cnt, N, E);

  // 3) two-level scan (plain kernels)
  int nBlocks = (N + 255) / 256;  // 40 <= 64
  scan1_kernel<<<nBlocks, 256, 0, stream>>>(cnt, off, bsum, N);
  scan23_kernel<<<nBlocks, 256, 0, stream>>>(off, bsum, nBlocks, N);

  // 4) scatter
  int eBlocks = (E + 255) / 256;  // 625
  scatter_kernel<<<eBlocks, 256, 0, stream>>>(src, dst, off, cur, bsrc, E);

  // 5) head-phased attention
  int nper = (N + 3) / 4;  // 2500 node-quads per head
  attn_kernel<<<nper * 4, 256, 0, stream>>>(qb, kv8, off, bsrc, oh, N, nper);

  // 6) combine (beta gate + column moments)
  combine_kernel<<<625, 256, 0, stream>>>(oh, skip, Wbeta, out2, colsum, colsq, N);

  // 7) finalize
  int total2 = N * D_DIM / 2;
  final_kernel<<<(total2 + 255) / 256, 256, 0, stream>>>(
      out2, colsum, colsq, gnw, gnb, gnms, x, (float*)d_out, total2, 1.f / (float)N);
}

// Round 9
// 216.086 us; speedup vs baseline: 1.7659x; 1.0598x over previous
//
#include <hip/hip_runtime.h>
#include <hip/hip_bf16.h>
#include <math.h>

// Problem constants: N=10000, E=160000, D=128, H=4, C=128, HC=512
#define D_DIM 128
#define HC_DIM 512

typedef __attribute__((ext_vector_type(8))) short bf16x8;
typedef __attribute__((ext_vector_type(4))) float f32x4;
typedef __attribute__((ext_vector_type(2))) float f32x2;

static __device__ __forceinline__ unsigned short f2bf(float f) {
  unsigned u = __float_as_uint(f);
  unsigned r = (u + 0x7fffu + ((u >> 16) & 1u)) >> 16;  // RNE
  return (unsigned short)r;
}
static __device__ __forceinline__ float bflo(unsigned u) {
  return __uint_as_float(u << 16);
}
static __device__ __forceinline__ float bfhi(unsigned u) {
  return __uint_as_float(u & 0xffff0000u);
}

// ---------------------------------------------------------------------------
// prep: cast x -> bf16; build Wt [1664][128] bf16 (coalesced source reads);
// bcat[1664]; zero counter region (cnt|cur|colsum|colsq).
// ---------------------------------------------------------------------------
__global__ void prep_kernel(const float* __restrict__ x,
                            const float* __restrict__ Wq, const float* __restrict__ Wk,
                            const float* __restrict__ Wv, const float* __restrict__ Wskip,
                            const float* __restrict__ bq, const float* __restrict__ bk,
                            const float* __restrict__ bv, const float* __restrict__ bskip,
                            unsigned short* __restrict__ xb,
                            unsigned short* __restrict__ wcat,
                            float* __restrict__ bcat,
                            int* __restrict__ zbase, int zwords, int N) {
  int t = blockIdx.x * 256 + threadIdx.x;
  int X4 = N * 32;  // x float4 count
  if (t < X4) {
    float4 f = *(const float4*)&x[t * 4];
    ushort4 o;
    o.x = f2bf(f.x); o.y = f2bf(f.y); o.z = f2bf(f.z); o.w = f2bf(f.w);
    *(ushort4*)&xb[t * 4] = o;
  } else if (t < X4 + 1664 * 128) {
    int widx = t - X4;
    if (widx < 3 * 65536) {
      int segi = widx >> 16;       // 0=q 1=k 2=v
      int r = widx & 65535;
      int kk = r >> 9;             // 0..127
      int m = r & 511;             // consecutive -> coalesced source read
      const float* W = (segi == 0) ? Wq : (segi == 1) ? Wk : Wv;
      wcat[(size_t)(segi * 512 + m) * 128 + kk] = f2bf(W[kk * 512 + m]);
    } else {
      int r = widx - 3 * 65536;    // < 16384
      int kk = r >> 7;
      int m = r & 127;
      wcat[(size_t)(1536 + m) * 128 + kk] = f2bf(Wskip[kk * 128 + m]);
    }
  } else if (t < X4 + 1664 * 128 + 1664) {
    int b = t - X4 - 1664 * 128;
    bcat[b] = (b < 512) ? bq[b] : (b < 1024) ? bk[b - 512]
            : (b < 1536) ? bv[b - 1024] : bskip[b - 1536];
  } else if (t < X4 + 1664 * 128 + 1664 + zwords) {
    zbase[t - X4 - 1664 * 128 - 1664] = 0;
  }
}

// ---------------------------------------------------------------------------
// LDS-free MFMA GEMM: [N x 1664] = Xb[N x 128] @ Wt[1664 x 128]^T + bcat.
// One wave per 64x64 output tile; A/B fragments are direct int4 global loads
// (16-row x 8-k chunks match the MFMA A/B layout exactly); X (2.5 MB) and
// Wt (0.43 MB) are L2-resident per XCD. No LDS, no barriers.
// cols 0-511 -> q bf16; 512-1535 -> k|v fp8; 1536-1663 -> skip fp32.
// ---------------------------------------------------------------------------
__global__ __launch_bounds__(256) void gemm_mfma_kernel(
    const unsigned short* __restrict__ Xb, const unsigned short* __restrict__ Wt,
    const float* __restrict__ bcat, unsigned short* __restrict__ qb,
    unsigned char* __restrict__ kv8, float* __restrict__ skip, int N) {
  const int tid = threadIdx.x;
  const int wave = tid >> 6, lane = tid & 63;
  const int l16 = lane & 15, quad = lane >> 4;
  const int row0 = (blockIdx.x * 4 + wave) * 64;  // wave's 64-row slab
  const int col0 = blockIdx.y * 64;               // wave's 64-col slab

  const unsigned short* xrow[4];
#pragma unroll
  for (int i = 0; i < 4; ++i) {
    int r = row0 + i * 16 + l16;
    if (r >= N) r = N - 1;  // clamp; stores masked later
    xrow[i] = Xb + (size_t)r * 128;
  }
  const unsigned short* wrow[4];
  float bias[4];
#pragma unroll
  for (int j = 0; j < 4; ++j) {
    int c = col0 + j * 16 + l16;
    wrow[j] = Wt + (size_t)c * 128;
    bias[j] = bcat[c];
  }

  f32x4 acc[4][4] = {};
#pragma unroll
  for (int kk = 0; kk < 4; ++kk) {
    int k0 = kk * 32 + quad * 8;
    bf16x8 a[4], b[4];
#pragma unroll
    for (int i = 0; i < 4; ++i) a[i] = *(const bf16x8*)(xrow[i] + k0);
#pragma unroll
    for (int j = 0; j < 4; ++j) b[j] = *(const bf16x8*)(wrow[j] + k0);
#pragma unroll
    for (int i = 0; i < 4; ++i)
#pragma unroll
      for (int j = 0; j < 4; ++j)
        acc[i][j] = __builtin_amdgcn_mfma_f32_16x16x32_bf16(a[i], b[j], acc[i][j], 0, 0, 0);
  }

  const int kind = (col0 < 512) ? 0 : (col0 < 1536) ? 1 : 2;  // wave-uniform
#pragma unroll
  for (int i = 0; i < 4; ++i) {
#pragma unroll
    for (int reg = 0; reg < 4; ++reg) {
      int r = row0 + i * 16 + quad * 4 + reg;
      if (r < N) {
#pragma unroll
        for (int j = 0; j < 4; ++j) {
          int cidx = col0 + j * 16 + l16;
          float val = acc[i][j][reg] + bias[j];
          if (kind == 0) {
            qb[(size_t)r * 512 + cidx] = f2bf(val);
          } else if (kind == 1) {
            int pk = __builtin_amdgcn_cvt_pk_fp8_f32(val, val, 0, false);
            kv8[(size_t)r * 1024 + cidx - 512] = (unsigned char)pk;
          } else {
            skip[(size_t)r * 128 + cidx - 1536] = val;
          }
        }
      }
    }
  }
}

// ---------------------------------------------------------------------------
// Edge bucketing: hist (own kernel — atomic burst contained), scan, scatter
// ---------------------------------------------------------------------------
__global__ void hist_kernel(const int* __restrict__ dst, int* __restrict__ cnt, int E) {
  int e = blockIdx.x * 256 + threadIdx.x;
  if (e < E) atomicAdd(&cnt[dst[e]], 1);
}

__global__ __launch_bounds__(256) void scan1_kernel(const int* __restrict__ cnt,
                                                    int* __restrict__ off,
                                                    int* __restrict__ bsum, int n) {
  __shared__ int wsum[4];
  int tid = threadIdx.x;
  int i = blockIdx.x * 256 + tid;
  int lane = tid & 63, w = tid >> 6;
  int v = (i < n) ? cnt[i] : 0;
  int x = v;
#pragma unroll
  for (int d = 1; d < 64; d <<= 1) {
    int y = __shfl_up(x, d);
    if (lane >= d) x += y;
  }
  if (lane == 63) wsum[w] = x;
  __syncthreads();
  int wo = 0;
  for (int j = 0; j < w; ++j) wo += wsum[j];
  if (i < n) off[i] = wo + x - v;
  if (tid == 255) bsum[blockIdx.x] = wo + x;
}

// each block redundantly scans bsum (nb <= 64), fixes its slice
__global__ __launch_bounds__(256) void scan23_kernel(int* __restrict__ off,
                                                     const int* __restrict__ bsum,
                                                     int nb, int n) {
  __shared__ int boffs[64];
  int tid = threadIdx.x;
  if (tid < 64) {
    int v = (tid < nb) ? bsum[tid] : 0;
    int x = v;
#pragma unroll
    for (int d = 1; d < 64; d <<= 1) {
      int y = __shfl_up(x, d);
      if (tid >= d) x += y;
    }
    boffs[tid] = x - v;
    if (tid == 63 && blockIdx.x == 0) off[n] = x;  // grand total
  }
  __syncthreads();
  int i = blockIdx.x * 256 + tid;
  if (i < n) off[i] += boffs[blockIdx.x];
}

__global__ void scatter_kernel(const int* __restrict__ src, const int* __restrict__ dst,
                               const int* __restrict__ off, int* __restrict__ cur,
                               int* __restrict__ bsrc, int E) {
  int e = blockIdx.x * 256 + threadIdx.x;
  if (e < E) {
    int d = dst[e];
    int p = off[d] + atomicAdd(&cur[d], 1);
    bsrc[p] = src[e];
  }
}

// ---------------------------------------------------------------------------
// Attention, head-phased, edge-per-16-lane-group.
// ---------------------------------------------------------------------------
__global__ __launch_bounds__(256) void attn_kernel(
    const unsigned short* __restrict__ qb, const unsigned char* __restrict__ kv8,
    const int* __restrict__ off, const int* __restrict__ bsrc,
    unsigned* __restrict__ oh, int N, int nper) {
  int bx = blockIdx.x;
  int head = bx / nper;
  int tid = threadIdx.x;
  int w = tid >> 6, lane = tid & 63;
  int node = (bx - head * nper) * 4 + w;
  if (node >= N) return;
  int g = lane >> 4, j = lane & 15;

  const float qscale = 0.08838834764831845f * 1.4426950408889634f;  // /sqrt(128)*log2e
  int4 qi = *(const int4*)(qb + (size_t)node * 512 + head * 128 + j * 8);
  float qf0 = bflo(qi.x) * qscale, qf1 = bfhi(qi.x) * qscale;
  float qf2 = bflo(qi.y) * qscale, qf3 = bfhi(qi.y) * qscale;
  float qf4 = bflo(qi.z) * qscale, qf5 = bfhi(qi.z) * qscale;
  float qf6 = bflo(qi.w) * qscale, qf7 = bfhi(qi.w) * qscale;

  const unsigned char* kb = kv8 + head * 128 + j * 8;
  int beg = off[node], end = off[node + 1];
  float lsum = 0.f;
  float o0 = 0.f, o1 = 0.f, o2 = 0.f, o3 = 0.f;
  float o4 = 0.f, o5 = 0.f, o6 = 0.f, o7 = 0.f;

  for (int idx = beg; idx < end; idx += 4) {
    int rem = end - idx;
    int e = bsrc[idx + ((g < rem) ? g : 0)];
    const unsigned char* kp = kb + (size_t)e * 1024;
    uint2 kw = *(const uint2*)kp;
    uint2 vw = *(const uint2*)(kp + 512);
    f32x2 k01 = __builtin_amdgcn_cvt_pk_f32_fp8(kw.x, false);
    f32x2 k23 = __builtin_amdgcn_cvt_pk_f32_fp8(kw.x, true);
    f32x2 k45 = __builtin_amdgcn_cvt_pk_f32_fp8(kw.y, false);
    f32x2 k67 = __builtin_amdgcn_cvt_pk_f32_fp8(kw.y, true);
    float p = qf0 * k01.x + qf1 * k01.y + qf2 * k23.x + qf3 * k23.y +
              qf4 * k45.x + qf5 * k45.y + qf6 * k67.x + qf7 * k67.y;
    p += __shfl_xor(p, 1);
    p += __shfl_xor(p, 2);
    p += __shfl_xor(p, 4);
    p += __shfl_xor(p, 8);
    float a = (g < rem) ? p : -1e30f;
    float wgt = exp2f(a);  // exp2(-1e30) = 0 for inactive slots
    f32x2 v01 = __builtin_amdgcn_cvt_pk_f32_fp8(vw.x, false);
    f32x2 v23 = __builtin_amdgcn_cvt_pk_f32_fp8(vw.x, true);
    f32x2 v45 = __builtin_amdgcn_cvt_pk_f32_fp8(vw.y, false);
    f32x2 v67 = __builtin_amdgcn_cvt_pk_f32_fp8(vw.y, true);
    lsum += wgt;
    o0 += wgt * v01.x; o1 += wgt * v01.y;
    o2 += wgt * v23.x; o3 += wgt * v23.y;
    o4 += wgt * v45.x; o5 += wgt * v45.y;
    o6 += wgt * v67.x; o7 += wgt * v67.y;
  }
  // cross-group butterfly (4 groups -> full sums on every lane)
  o0 += __shfl_xor(o0, 16); o0 += __shfl_xor(o0, 32);
  o1 += __shfl_xor(o1, 16); o1 += __shfl_xor(o1, 32);
  o2 += __shfl_xor(o2, 16); o2 += __shfl_xor(o2, 32);
  o3 += __shfl_xor(o3, 16); o3 += __shfl_xor(o3, 32);
  o4 += __shfl_xor(o4, 16); o4 += __shfl_xor(o4, 32);
  o5 += __shfl_xor(o5, 16); o5 += __shfl_xor(o5, 32);
  o6 += __shfl_xor(o6, 16); o6 += __shfl_xor(o6, 32);
  o7 += __shfl_xor(o7, 16); o7 += __shfl_xor(o7, 32);
  lsum += __shfl_xor(lsum, 16); lsum += __shfl_xor(lsum, 32);
  float inv = 1.f / (lsum + 1e-16f);
  if (g == 0) {
    unsigned d0 = (unsigned)f2bf(o0 * inv) | ((unsigned)f2bf(o1 * inv) << 16);
    unsigned d1 = (unsigned)f2bf(o2 * inv) | ((unsigned)f2bf(o3 * inv) << 16);
    unsigned d2 = (unsigned)f2bf(o4 * inv) | ((unsigned)f2bf(o5 * inv) << 16);
    unsigned d3 = (unsigned)f2bf(o6 * inv) | ((unsigned)f2bf(o7 * inv) << 16);
    int4 st; st.x = (int)d0; st.y = (int)d1; st.z = (int)d2; st.w = (int)d3;
    *(int4*)(oh + ((size_t)head * N + node) * 64 + j * 4) = st;
  }
}

// ---------------------------------------------------------------------------
// combine: beta gate + head-mean + out2 + column sums.
// 625 blocks x 256; block-level LDS reduction -> 1 atomic/block/column.
// ---------------------------------------------------------------------------
__global__ __launch_bounds__(256) void combine_kernel(
    const unsigned* __restrict__ oh, const float* __restrict__ skip,
    const float* __restrict__ Wbeta, float* __restrict__ out2,
    float* __restrict__ colsum, float* __restrict__ colsq, int N) {
  int tid = threadIdx.x;
  int lane = tid & 63, w = tid >> 6;
  int wid = blockIdx.x * 4 + w;  // 0..2499
  float2 wb0 = *(const float2*)&Wbeta[lane * 2];
  float2 wb1 = *(const float2*)&Wbeta[128 + lane * 2];
  float2 wb2 = *(const float2*)&Wbeta[256 + lane * 2];
  float cs0 = 0.f, cq0 = 0.f, cs1 = 0.f, cq1 = 0.f;
#pragma unroll
  for (int k = 0; k < 4; ++k) {
    int n = wid + k * 2500;
    if (n < N) {
      unsigned h0 = oh[((size_t)0 * N + n) * 64 + lane];
      unsigned h1 = oh[((size_t)1 * N + n) * 64 + lane];
      unsigned h2 = oh[((size_t)2 * N + n) * 64 + lane];
      unsigned h3 = oh[((size_t)3 * N + n) * 64 + lane];
      float a0 = 0.25f * (bflo(h0) + bflo(h1) + bflo(h2) + bflo(h3));
      float a1 = 0.25f * (bfhi(h0) + bfhi(h1) + bfhi(h2) + bfhi(h3));
      float2 s = *(const float2*)&skip[(size_t)n * 128 + lane * 2];
      float p = a0 * wb0.x + s.x * wb1.x + (a0 - s.x) * wb2.x +
                a1 * wb0.y + s.y * wb1.y + (a1 - s.y) * wb2.y;
#pragma unroll
      for (int dmask = 1; dmask < 64; dmask <<= 1) p += __shfl_xor(p, dmask);
      float beta = 1.f / (1.f + __expf(-p));
      float o0 = beta * s.x + (1.f - beta) * a0;
      float o1 = beta * s.y + (1.f - beta) * a1;
      float2 ov; ov.x = o0; ov.y = o1;
      *(float2*)&out2[(size_t)n * 128 + lane * 2] = ov;
      cs0 += o0; cq0 += o0 * o0;
      cs1 += o1; cq1 += o1 * o1;
    }
  }
  __shared__ float red[4][128];
  __shared__ float redq[4][128];
  red[w][lane * 2] = cs0;
  red[w][lane * 2 + 1] = cs1;
  redq[w][lane * 2] = cq0;
  redq[w][lane * 2 + 1] = cq1;
  __syncthreads();
  if (w == 0) {
    int c = lane * 2;
    float s0 = red[0][c] + red[1][c] + red[2][c] + red[3][c];
    float s1 = red[0][c + 1] + red[1][c + 1] + red[2][c + 1] + red[3][c + 1];
    float q0 = redq[0][c] + redq[1][c] + redq[2][c] + redq[3][c];
    float q1 = redq[0][c + 1] + redq[1][c + 1] + redq[2][c + 1] + redq[3][c + 1];
    atomicAdd(&colsum[c], s0);
    atomicAdd(&colsum[c + 1], s1);
    atomicAdd(&colsq[c], q0);
    atomicAdd(&colsq[c + 1], q1);
  }
}

// ---------------------------------------------------------------------------
// finalize: inline redundant column stats + groupnorm + exact GELU + residual
// ---------------------------------------------------------------------------
__global__ void final_kernel(const float* __restrict__ out2,
                             const float* __restrict__ colsum,
                             const float* __restrict__ colsq,
                             const float* __restrict__ gnw,
                             const float* __restrict__ gnb,
                             const float* __restrict__ gnms,
                             const float* __restrict__ x,
                             float* __restrict__ y, int total2, float invN) {
  int i = blockIdx.x * 256 + threadIdx.x;
  if (i < total2) {
    int c = (i & 63) * 2;
    float2 cs = *(const float2*)&colsum[c];
    float2 cq = *(const float2*)&colsq[c];
    float2 gw = *(const float2*)&gnw[c];
    float2 gb = *(const float2*)&gnb[c];
    float2 gs = *(const float2*)&gnms[c];
    float mean0 = cs.x * invN, mean1 = cs.y * invN;
    float var0 = cq.x * invN - mean0 * mean0 * gs.x * (2.f - gs.x);
    float var1 = cq.y * invN - mean1 * mean1 * gs.y * (2.f - gs.y);
    float mul0 = gw.x / sqrtf(var0 + 1e-5f);
    float mul1 = gw.y / sqrtf(var1 + 1e-5f);
    float2 o = *(const float2*)&out2[i * 2];
    float2 xx = *(const float2*)&x[i * 2];
    float t0 = (o.x - gs.x * mean0) * mul0 + gb.x;
    float t1 = (o.y - gs.y * mean1) * mul1 + gb.y;
    float g0 = 0.5f * t0 * (1.f + erff(t0 * 0.70710678118654752f));
    float g1 = 0.5f * t1 * (1.f + erff(t1 * 0.70710678118654752f));
    float2 r; r.x = g0 + xx.x; r.y = g1 + xx.y;
    *(float2*)&y[i * 2] = r;
  }
}

extern "C" void kernel_launch(void* const* d_in, const int* in_sizes, int n_in,
                              void* d_out, int out_size, void* d_ws, size_t ws_size,
                              hipStream_t stream) {
  const float* x     = (const float*)d_in[0];
  const int*   ei    = (const int*)d_in[1];
  const float* Wq    = (const float*)d_in[2];
  const float* bq    = (const float*)d_in[3];
  const float* Wk    = (const float*)d_in[4];
  const float* bk    = (const float*)d_in[5];
  const float* Wv    = (const float*)d_in[6];
  const float* bv    = (const float*)d_in[7];
  const float* Wskip = (const float*)d_in[8];
  const float* bskip = (const float*)d_in[9];
  const float* Wbeta = (const float*)d_in[10];
  const float* gnw   = (const float*)d_in[11];
  const float* gnb   = (const float*)d_in[12];
  const float* gnms  = (const float*)d_in[13];

  const int N = in_sizes[0] / D_DIM;   // 10000
  const int E = in_sizes[1] / 2;       // 160000
  const int* src = ei;
  const int* dst = ei + E;

  // workspace carve-up (aliases: xb over oh — disjoint lifetimes)
  char* p = (char*)d_ws;
  unsigned short* qb  = (unsigned short*)p; p += (size_t)N * 512 * 2;     // q bf16
  unsigned char*  kv8 = (unsigned char*)p;  p += (size_t)N * 1024;        // k|v fp8
  unsigned*       oh  = (unsigned*)p;       p += (size_t)4 * N * 64 * 4;  // per-head out bf16x2
  float*          skip = (float*)p;         p += (size_t)N * 128 * 4;
  float*          out2 = (float*)p;         p += (size_t)N * 128 * 4;
  // contiguous zero region: cnt | cur | colsum | colsq
  int*   cnt    = (int*)p;   p += (size_t)N * 4;
  int*   cur    = (int*)p;   p += (size_t)N * 4;
  float* colsum = (float*)p; p += 128 * 4;
  float* colsq  = (float*)p; p += 128 * 4;
  int zwords = 2 * N + 256;
  int* off    = (int*)p;   p += (size_t)(N + 16) * 4;  // padded: keep 16B align
  int* bsum   = (int*)p;   p += 64 * 4;
  int* bsrc   = (int*)p;   p += (size_t)E * 4;
  unsigned short* wcat = (unsigned short*)p; p += (size_t)1664 * 128 * 2;
  float* bcat = (float*)p; p += 1664 * 4;
  unsigned short* xb = (unsigned short*)oh;  // alias: xb dead before oh written

  // 1) prep (casts + weight transpose + zeroing)
  int prepTotal = N * 32 + 1664 * 128 + 1664 + zwords;
  prep_kernel<<<(prepTotal + 255) / 256, 256, 0, stream>>>(
      x, Wq, Wk, Wv, Wskip, bq, bk, bv, bskip, xb, wcat, bcat, cnt, zwords, N);

  // 2) LDS-free QKV+skip GEMM (one wave per 64x64 tile)
  //    grid: 40 row-quads (256 rows each) x 26 col-tiles of 64
  gemm_mfma_kernel<<<dim3(40, 26), 256, 0, stream>>>(
      xb, wcat, bcat, qb, kv8, skip, N);

  // 3) histogram (separate: atomic burst contained)
  int eBlocks = (E + 255) / 256;  // 625
  hist_kernel<<<eBlocks, 256, 0, stream>>>(dst, cnt, E);

  // 4) two-level scan
  int nBlocks = (N + 255) / 256;  // 40 <= 64
  scan1_kernel<<<nBlocks, 256, 0, stream>>>(cnt, off, bsum, N);
  scan23_kernel<<<nBlocks, 256, 0, stream>>>(off, bsum, nBlocks, N);

  // 5) scatter
  scatter_kernel<<<eBlocks, 256, 0, stream>>>(src, dst, off, cur, bsrc, E);

  // 6) head-phased attention
  int nper = (N + 3) / 4;  // 2500 node-quads per head
  attn_kernel<<<nper * 4, 256, 0, stream>>>(qb, kv8, off, bsrc, oh, N, nper);

  // 7) combine (beta gate + column moments)
  combine_kernel<<<625, 256, 0, stream>>>(oh, skip, Wbeta, out2, colsum, colsq, N);

  // 8) finalize
  int total2 = N * D_DIM / 2;
  final_kernel<<<(total2 + 255) / 256, 256, 0, stream>>>(
      out2, colsum, colsq, gnw, gnb, gnms, x, (float*)d_out, total2, 1.f / (float)N);
}